// Round 5
// baseline (161.440 us; speedup 1.0000x reference)
//
#include <hip/hip_runtime.h>
#include <hip/hip_bf16.h>
#include <math.h>

// ---------------- CQT constants ----------------
#define NBINS    252
#define NFRAMES  456
#define HOPSZ    484
#define SIGLEN   220500
#define TSTART0  (-34688)      // most negative tap (T0=34682 rounded up to mult of 8)
#define KMAX     69632         // global tap-index extent (68 chunks x 1024)
#define KB8      8704          // KMAX / 8  (k-blocks of 8)
#define NFT      32            // frame tiles of 16 -> covers 512 frames (456 used)
#define SRD      44100.0
#define FMIND    32.70319566257483
#define MAXCH    264
#define SC       32            // K-steps (x32 taps) per chunk

typedef unsigned short ushort_t;
typedef __attribute__((ext_vector_type(8))) short bf16x8;
typedef __attribute__((ext_vector_type(4))) float f32x4;

struct ChunkTab { int2 e[MAXCH]; };   // .x = group, .y = jrel (chunk tap start - TSTART0, mult of 8)
struct GroupC {                        // per-group bases + per-bin-in-group ratio + exact T
  float fosg[16];                      // freq/SR for bin 16g
  float invLg[16];                     // 1/L for bin 16g
  float ratio[16];                     // 2^(bl/36)
  ushort_t Tfu[256];                   // per-bin T (0 for nonexistent bins)
};
struct FinC { float nrm[256]; int2 gt[16]; };  // per-bin norm; per-group {chunk0, nchunks}

__device__ __forceinline__ ushort_t f2bf(float x) {
  __hip_bfloat16 h = __float2bfloat16(x);
  return *reinterpret_cast<ushort_t*>(&h);
}

// ---------------- transpose: f32 signal -> MFMA-fragment-tiled bf16 A matrix ---------
// At[ft][kk>>3][f&15][kk&7], elem (f, kk) = sig[f*484 + TSTART0 + kk] (0 outside).
// grid (68 kb-groups of 128, 32 ftiles), 256 thr. LDS-staged: coalesced global reads
// (row-contiguous) and fully-coalesced 4KB-contiguous tiled writes.
__global__ __launch_bounds__(256) void transpose_kernel(const float* __restrict__ sig,
                                                        ushort_t* __restrict__ At) {
  __shared__ ushort_t lds[16][1032];          // +8 pad: write banks 2-way (free)
  const int kbg = blockIdx.x;                 // 0..67
  const int ft  = blockIdx.y;                 // 0..31
  const int t   = threadIdx.x;

  // load phase: thread (r = t&15, c16 = t>>4): row f = ft*16+r, 64 samples
  {
    const int r = t & 15, c16 = t >> 4;
    const int sbase = (ft * 16 + r) * HOPSZ + TSTART0 + kbg * 1024 + c16 * 64;
#pragma unroll
    for (int cc = 0; cc < 16; ++cc) {
      const int s = sbase + cc * 4;
      ushort_t o0, o1, o2, o3;
      if (s >= 0 && s + 3 < SIGLEN) {
        const float4 v = *reinterpret_cast<const float4*>(sig + s);
        o0 = f2bf(v.x); o1 = f2bf(v.y); o2 = f2bf(v.z); o3 = f2bf(v.w);
      } else {
        o0 = (s + 0 >= 0 && s + 0 < SIGLEN) ? f2bf(sig[s + 0]) : (ushort_t)0;
        o1 = (s + 1 >= 0 && s + 1 < SIGLEN) ? f2bf(sig[s + 1]) : (ushort_t)0;
        o2 = (s + 2 >= 0 && s + 2 < SIGLEN) ? f2bf(sig[s + 2]) : (ushort_t)0;
        o3 = (s + 3 >= 0 && s + 3 < SIGLEN) ? f2bf(sig[s + 3]) : (ushort_t)0;
      }
      const int col = c16 * 64 + cc * 4;
      lds[r][col + 0] = o0; lds[r][col + 1] = o1;
      lds[r][col + 2] = o2; lds[r][col + 3] = o3;
    }
  }
  __syncthreads();

  // write phase: 8 rounds x 16B/thread, output contiguous 4KB per round
  const size_t OB = ((size_t)ft * KB8 + (size_t)kbg * 128) * 128;   // elems
  const int fr = t & 15;
#pragma unroll
  for (int q = 0; q < 8; ++q) {
    const int kb = q * 16 + (t >> 4);         // 0..127 (within kb-group)
    const uint4 v = *reinterpret_cast<const uint4*>(&lds[fr][kb * 8]);
    *reinterpret_cast<uint4*>(At + OB + ((size_t)kb * 16 + fr) * 8) = v;
  }
}

// ---------------- fused: generate chunk bank in LDS, then MFMA ----------------
// grid (2 frame-halves, nch), 512 thr = 8 waves. Phase 1: chunk B fragments
// (32 ks x [kr 512 | ki 512] bf16) into 64 KB LDS (float-only math, host consts).
// Phase 2: wave w -> frames st*256 + w*32 .. +31 (two 16-row A tiles); A loads are
// single dwordx4/lane, 1KB contiguous per wave-load (fragment-tiled At).
__global__ __launch_bounds__(512) void cqt_fused(const ushort_t* __restrict__ At,
                                                 float2* __restrict__ partial,
                                                 ChunkTab tab, GroupC gc) {
  __shared__ ushort_t blds[SC * 1024];        // 64 KB
  const int tid  = threadIdx.x;
  const int lane = tid & 63;
  const int bl   = lane & 15, kb = lane >> 4;
  const int c    = blockIdx.y;
  const int st   = blockIdx.x;
  const int g    = tab.e[c].x, jrel = tab.e[c].y;

  // ---- phase 1: bank generation ----
  {
    const float fos  = gc.fosg[g]  * gc.ratio[bl];
    const float invL = gc.invLg[g] * gc.ratio[bl];
    const float Tf   = (float)gc.Tfu[g * 16 + bl];
    const int ksub = tid >> 6;                 // 0..7
#pragma unroll
    for (int kq = 0; kq < 4; ++kq) {
      const int ks = ksub + kq * 8;
      const int t0 = TSTART0 + jrel + ks * 32 + kb * 8;
      union { ushort_t u[8]; uint4 v; } pr, pi;
#pragma unroll
      for (int j = 0; j < 8; ++j) {
        const float tt = (float)(t0 + j);
        float kr = 0.0f, ki = 0.0f;
        if (fabsf(tt) <= Tf) {
          float w = 0.5f + 0.5f * __cosf(6.2831853f * (tt * invL));
          float r = fos * tt; r -= rintf(r);   // phase mod 1
          float s, cc2; __sincosf(6.2831853f * r, &s, &cc2);
          kr = w * cc2; ki = w * s;
        }
        pr.u[j] = f2bf(kr); pi.u[j] = f2bf(ki);
      }
      *reinterpret_cast<uint4*>(&blds[ks * 1024 + lane * 8])       = pr.v;
      *reinterpret_cast<uint4*>(&blds[ks * 1024 + 512 + lane * 8]) = pi.v;
    }
  }
  __syncthreads();

  // ---- phase 2: MFMA over 32 K-steps ----
  const int w = tid >> 6;
  const int fbase = st * 256 + w * 32;
  const int ft0 = fbase >> 4;
  // A'(f,kk) at ((f>>4)*KB8 + (kk>>3))*128 + (f&15)*8 + (kk&7); kk = jrel + ks*32 + kb*8 + j
  const ushort_t* pA0 = At + (((size_t)ft0 * KB8 + (jrel >> 3) + kb) * 16 + bl) * 8;
  const ushort_t* pA1 = pA0 + (size_t)KB8 * 128;

  f32x4 ar0 = {0.f, 0.f, 0.f, 0.f};
  f32x4 ai0 = ar0, ar1 = ar0, ai1 = ar0;

#pragma unroll 8
  for (int ks = 0; ks < SC; ++ks) {
    union { uint4 q; bf16x8 v; } a0, a1, bk, bi;
    a0.q = *reinterpret_cast<const uint4*>(pA0 + (size_t)ks * 512);
    a1.q = *reinterpret_cast<const uint4*>(pA1 + (size_t)ks * 512);
    bk.q = *reinterpret_cast<const uint4*>(&blds[ks * 1024 + lane * 8]);
    bi.q = *reinterpret_cast<const uint4*>(&blds[ks * 1024 + 512 + lane * 8]);
    ar0 = __builtin_amdgcn_mfma_f32_16x16x32_bf16(a0.v, bk.v, ar0, 0, 0, 0);
    ai0 = __builtin_amdgcn_mfma_f32_16x16x32_bf16(a0.v, bi.v, ai0, 0, 0, 0);
    ar1 = __builtin_amdgcn_mfma_f32_16x16x32_bf16(a1.v, bk.v, ar1, 0, 0, 0);
    ai1 = __builtin_amdgcn_mfma_f32_16x16x32_bf16(a1.v, bi.v, ai1, 0, 0, 0);
  }

  // C/D: col = lane&15 (bin-in-group), row = (lane>>4)*4 + reg  [m89-verified]
  float2* pp = partial + ((size_t)(c * 2 + st) * 256 + w * 32) * 16 + bl;
  const int row = kb * 4;
#pragma unroll
  for (int r = 0; r < 4; ++r) {
    pp[(size_t)(row + r) * 16]      = make_float2(ar0[r], ai0[r]);
    pp[(size_t)(row + r + 16) * 16] = make_float2(ar1[r], ai1[r]);
  }
}

// ---------------- finalize: cooperative slab-sum, magnitude + norm ----------------
// grid (16 groups, 2 halves, 4 frame-quarters), 256 thr. Per chunk iter the block
// reads a contiguous 8 KB slab (fully coalesced); each thread owns 4 outputs.
__global__ __launch_bounds__(256) void fin_kernel(const float2* __restrict__ partial,
                                                  float* __restrict__ out, FinC fc) {
  const int g  = blockIdx.x;
  const int st = blockIdx.y;
  const int fq = blockIdx.z;
  const int t  = threadIdx.x;
  const int c0 = fc.gt[g].x, nc = fc.gt[g].y;

  float cr[4] = {0.f, 0.f, 0.f, 0.f}, ci[4] = {0.f, 0.f, 0.f, 0.f};
  for (int c = c0; c < c0 + nc; ++c) {
    const float4* b4 = reinterpret_cast<const float4*>(
        partial + (size_t)(c * 2 + st) * 4096 + fq * 1024 + t * 4);
    const float4 v0 = b4[0], v1 = b4[1];
    cr[0] += v0.x; ci[0] += v0.y; cr[1] += v0.z; ci[1] += v0.w;
    cr[2] += v1.x; ci[2] += v1.y; cr[3] += v1.z; ci[3] += v1.w;
  }
#pragma unroll
  for (int i = 0; i < 4; ++i) {
    const int flat = fq * 1024 + t * 4 + i;
    const int fl = flat >> 4, bl = flat & 15;
    const int f = st * 256 + fl, b = g * 16 + bl;
    if (f < NFRAMES && b < NBINS)
      out[(size_t)b * NFRAMES + f] = fc.nrm[b] * sqrtf(cr[i] * cr[i] + ci[i] * ci[i]);
  }
}

// ---------------- launch ----------------
extern "C" void kernel_launch(void* const* d_in, const int* in_sizes, int n_in,
                              void* d_out, int out_size, void* d_ws, size_t ws_size,
                              hipStream_t stream) {
  const float* sig = (const float*)d_in[0];
  float* out = (float*)d_out;
  char* ws = (char*)d_ws;

  // ---- host-side constant tables (pure arithmetic, identical every call) ----
  ChunkTab ctab; GroupC gc; FinC fc;
  const double PI = 3.14159265358979323846;
  const double Q = 1.0 / (exp2(1.0 / 36.0) - 1.0);
  int nch = 0;
  for (int g = 0; g < 16; ++g) {
    double freq = FMIND * exp2((double)(16 * g) / 36.0);
    double L = Q * SRD / freq;
    int T = (int)(L * 0.5);
    int r = (8 - (T & 7)) & 7;
    int tstart = -(T + r);                    // mult of 8
    int ntaps = 2 * T + 1 + r;
    int chunks = (ntaps + 1023) / 1024;
    gc.fosg[g] = (float)(freq / SRD);
    gc.invLg[g] = (float)(1.0 / L);
    fc.gt[g].x = nch; fc.gt[g].y = chunks;
    int jrel0 = tstart - TSTART0;             // >= 0, mult of 8
    for (int k = 0; k < chunks; ++k) {
      ctab.e[nch].x = g; ctab.e[nch].y = jrel0 + k * 1024; ++nch;
    }
  }
  for (int i = nch; i < MAXCH; ++i) { ctab.e[i].x = 0; ctab.e[i].y = 0; }
  for (int bl = 0; bl < 16; ++bl) gc.ratio[bl] = (float)exp2((double)bl / 36.0);
  for (int b = 0; b < 256; ++b) {
    if (b < NBINS) {
      double freq = FMIND * exp2((double)b / 36.0);
      double L = Q * SRD / freq;
      int T = (int)(L * 0.5);
      double N = (double)(2 * T + 1);
      double win_sum = 0.5 * N - 0.5 * (sin(PI * (N - L) / L) / sin(PI / L));
      gc.Tfu[b] = (ushort_t)T;
      fc.nrm[b] = (float)(1.0 / (win_sum * sqrt(L)));
    } else {
      gc.Tfu[b] = 0; fc.nrm[b] = 0.0f;
    }
  }

  // ---- ws layout: At (71.3 MB) | partial (nch*2 slabs x 32 KB) ----
  ushort_t* At = (ushort_t*)ws;
  size_t off = (size_t)NFT * KB8 * 128 * sizeof(ushort_t);   // 71,303,168
  float2* partial = (float2*)(ws + off);

  transpose_kernel<<<dim3(68, NFT), 256, 0, stream>>>(sig, At);
  cqt_fused<<<dim3(2, nch), 512, 0, stream>>>(At, partial, ctab, gc);
  fin_kernel<<<dim3(16, 2, 4), 256, 0, stream>>>(partial, out, fc);
}

// Round 9
// 132.135 us; speedup vs baseline: 1.2218x; 1.2218x over previous
//
#include <hip/hip_runtime.h>
#include <hip/hip_bf16.h>
#include <math.h>

// ---------------- CQT constants ----------------
#define NBINS    252
#define NFRAMES  456
#define HOPSZ    484
#define SIGLEN   220500
#define TSTART0  (-34688)      // most negative tap (T0=34682 rounded up to mult of 8)
#define SRD      44100.0
#define FMIND    32.70319566257483
#define MAXCH    264
#define ASPAN    31520         // staged samples per block: 63*484+1024 = 31516 -> 31520

typedef unsigned short ushort_t;
typedef __attribute__((ext_vector_type(8))) short bf16x8;
typedef __attribute__((ext_vector_type(4))) float f32x4;

struct ChunkTab { int2 e[MAXCH]; };   // .x = group, .y = jrel (chunk tap start - TSTART0, mult of 8)
struct GroupC {                        // per-group bases + per-bin-in-group ratio + exact T
  float fosg[16];                      // freq/SR for bin 16g
  float invLg[16];                     // 1/L for bin 16g
  float ratio[16];                     // 2^(bl/36)
  ushort_t Tfu[256];                   // per-bin T (0 for nonexistent bins)
};
struct FinC { float nrm[256]; int2 gt[16]; };  // per-bin norm; per-group {chunk0, nchunks}

__device__ __forceinline__ ushort_t f2bf(float x) {
  __hip_bfloat16 h = __float2bfloat16(x);
  return *reinterpret_cast<ushort_t*>(&h);
}

// ---- B-fragment generation for one 4-ks sub-phase (one thread: 4 taps, kr+ki) ----
// buf layout per ks: [frag(0=kr,1=ki)*512 + lane*8 + j] bf16, ks-major 1024 elems.
__device__ __forceinline__ void gen_phase(ushort_t* __restrict__ buf, int sc,
                                          int tbase, int gks, int glane, int gj0,
                                          float fos, float invL, float Tf) {
  const int t0 = tbase + (sc * 4 + gks) * 32 + (glane >> 4) * 8 + gj0;
  ushort_t pr[4], pi[4];
#pragma unroll
  for (int j = 0; j < 4; ++j) {
    const float tt = (float)(t0 + j);
    float kr = 0.0f, ki = 0.0f;
    if (fabsf(tt) <= Tf) {
      float wv = 0.5f + 0.5f * __cosf(6.2831853f * (tt * invL));
      float r = fos * tt; r -= rintf(r);             // phase mod 1
      float sn, cs; __sincosf(6.2831853f * r, &sn, &cs);
      kr = wv * cs; ki = wv * sn;
    }
    pr[j] = f2bf(kr); pi[j] = f2bf(ki);
  }
  *reinterpret_cast<uint2*>(&buf[gks * 1024 + glane * 8 + gj0])       = *reinterpret_cast<uint2*>(pr);
  *reinterpret_cast<uint2*>(&buf[gks * 1024 + 512 + glane * 8 + gj0]) = *reinterpret_cast<uint2*>(pi);
}

// ---------------- fused: stage signal segment + gen B in LDS, MFMA ----------------
// grid (8 frame-tiles of 64, nch chunks), 512 thr = 8 waves = 4 frame-quarters x {re,im}.
// A staged once per block as a LINEAR bf16 signal segment (63 KB) -> frames overlap in
// storage (the 63 MB logical A matrix never exists). B double-buffered 4-ks sub-phases.
__global__ __launch_bounds__(512) void cqt_fused(const float* __restrict__ sig,
                                                 float* __restrict__ partial,
                                                 ChunkTab tab, GroupC gc) {
  __shared__ ushort_t Alds[ASPAN];        // 63,040 B
  __shared__ ushort_t Blds[2][4096];      // 2 x 8,192 B  (4 ks x 1024)

  const int tid = threadIdx.x;
  const int c = blockIdx.y, ft8 = blockIdx.x;
  const int g = tab.e[c].x, jrel = tab.e[c].y;
  const int f0 = ft8 * 64;
  const int S0 = f0 * HOPSZ + TSTART0 + jrel;        // mult of 8 by construction

  // ---- stage A: f32 signal [S0, S0+ASPAN) -> bf16 LDS (L2-resident source) ----
  for (int rr = 0; rr < 16; ++rr) {
    const int i = (rr * 512 + tid) * 4;
    if (i < ASPAN) {
      const int s = S0 + i;
      float x0, x1, x2, x3;
      if (s >= 0 && s + 3 < SIGLEN) {                // 16B-aligned fast path
        const float4 v = *reinterpret_cast<const float4*>(sig + s);
        x0 = v.x; x1 = v.y; x2 = v.z; x3 = v.w;
      } else {
        x0 = (s + 0 >= 0 && s + 0 < SIGLEN) ? sig[s + 0] : 0.0f;
        x1 = (s + 1 >= 0 && s + 1 < SIGLEN) ? sig[s + 1] : 0.0f;
        x2 = (s + 2 >= 0 && s + 2 < SIGLEN) ? sig[s + 2] : 0.0f;
        x3 = (s + 3 >= 0 && s + 3 < SIGLEN) ? sig[s + 3] : 0.0f;
      }
      ushort_t* d = &Alds[i];
      d[0] = f2bf(x0); d[1] = f2bf(x1); d[2] = f2bf(x2); d[3] = f2bf(x3);
    }
  }

  // ---- per-thread gen constants (thread covers one (ks4, lane, j-half) slot) ----
  const int glane = tid & 63;
  const int gks = (tid >> 6) & 3;
  const int gj0 = (tid >> 8) * 4;
  const int gbl = glane & 15;
  const float fos  = gc.fosg[g]  * gc.ratio[gbl];
  const float invL = gc.invLg[g] * gc.ratio[gbl];
  const float Tf   = (float)gc.Tfu[g * 16 + gbl];
  const int tbase = TSTART0 + jrel;

  // ---- MFMA lane roles: wave (fq, ri); lane (bl=frame-row, kb=k-subblock) ----
  const int lane = tid & 63;
  const int w = tid >> 6;
  const int fq = w & 3, ri = w >> 2;
  const int bl = lane & 15, kb = lane >> 4;
  const ushort_t* Ab = &Alds[(fq * 16 + bl) * HOPSZ + kb * 8];

  f32x4 acc = {0.f, 0.f, 0.f, 0.f};

  gen_phase(Blds[0], 0, tbase, gks, glane, gj0, fos, invL, Tf);
  __syncthreads();

  for (int sc = 0; sc < 8; ++sc) {
    if (sc < 7)
      gen_phase(Blds[(sc + 1) & 1], sc + 1, tbase, gks, glane, gj0, fos, invL, Tf);
    const ushort_t* Bb = &Blds[sc & 1][ri * 512 + lane * 8];
#pragma unroll
    for (int k4 = 0; k4 < 4; ++k4) {
      const int ks = sc * 4 + k4;
      union { uint2 q[2]; bf16x8 v; } a;
      a.q[0] = *reinterpret_cast<const uint2*>(Ab + ks * 32);      // 8B-aligned
      a.q[1] = *reinterpret_cast<const uint2*>(Ab + ks * 32 + 4);
      union { uint4 q; bf16x8 v; } b;
      b.q = *reinterpret_cast<const uint4*>(Bb + k4 * 1024);
      acc = __builtin_amdgcn_mfma_f32_16x16x32_bf16(a.v, b.v, acc, 0, 0, 0);
    }
    __syncthreads();
  }

  // C/D: col = lane&15 (bin), row = kb*4 + r (frame-in-tile)  [m89-verified]
  // partial flat: ((c*8+ft8)*2 + ri)*1024 + fq*256 + row*16 + bl
  float* pp = partial + (size_t)(((c * 8 + ft8) * 2 + ri) * 1024 + fq * 256 + bl);
#pragma unroll
  for (int r = 0; r < 4; ++r)
    pp[(kb * 4 + r) * 16] = acc[r];
}

// ---------------- finalize: sum partials over a group's chunks, magnitude + norm ----
// grid (16 groups, 8 frame-tiles), 256 thr; float4 reads fully coalesced.
__global__ __launch_bounds__(256) void fin_kernel(const float* __restrict__ partial,
                                                  float* __restrict__ out, FinC fc) {
  const int g = blockIdx.x, ft8 = blockIdx.y;
  const int t = threadIdx.x;
  const int c0 = fc.gt[g].x, nc = fc.gt[g].y;

  float cr[4] = {0.f, 0.f, 0.f, 0.f}, ci[4] = {0.f, 0.f, 0.f, 0.f};
  for (int c = c0; c < c0 + nc; ++c) {
    const float4 vr = *reinterpret_cast<const float4*>(
        partial + (size_t)((c * 8 + ft8) * 2 + 0) * 1024 + t * 4);
    const float4 vi = *reinterpret_cast<const float4*>(
        partial + (size_t)((c * 8 + ft8) * 2 + 1) * 1024 + t * 4);
    cr[0] += vr.x; cr[1] += vr.y; cr[2] += vr.z; cr[3] += vr.w;
    ci[0] += vi.x; ci[1] += vi.y; ci[2] += vi.z; ci[3] += vi.w;
  }
#pragma unroll
  for (int i = 0; i < 4; ++i) {
    const int j = t * 4 + i;
    const int f = ft8 * 64 + (j >> 4);
    const int b = g * 16 + (j & 15);
    if (f < NFRAMES && b < NBINS)
      out[(size_t)b * NFRAMES + f] = fc.nrm[b] * sqrtf(cr[i] * cr[i] + ci[i] * ci[i]);
  }
}

// ---------------- launch ----------------
extern "C" void kernel_launch(void* const* d_in, const int* in_sizes, int n_in,
                              void* d_out, int out_size, void* d_ws, size_t ws_size,
                              hipStream_t stream) {
  const float* sig = (const float*)d_in[0];
  float* out = (float*)d_out;

  // ---- host-side constant tables (pure arithmetic, identical every call) ----
  ChunkTab ctab; GroupC gc; FinC fc;
  const double PI = 3.14159265358979323846;
  const double Q = 1.0 / (exp2(1.0 / 36.0) - 1.0);
  int nch = 0;
  for (int g = 0; g < 16; ++g) {
    double freq = FMIND * exp2((double)(16 * g) / 36.0);
    double L = Q * SRD / freq;
    int T = (int)(L * 0.5);
    int r = (8 - (T & 7)) & 7;
    int tstart = -(T + r);                    // mult of 8
    int ntaps = 2 * T + 1 + r;
    int chunks = (ntaps + 1023) / 1024;
    gc.fosg[g] = (float)(freq / SRD);
    gc.invLg[g] = (float)(1.0 / L);
    fc.gt[g].x = nch; fc.gt[g].y = chunks;
    int jrel0 = tstart - TSTART0;             // >= 0, mult of 8
    for (int k = 0; k < chunks; ++k) {
      ctab.e[nch].x = g; ctab.e[nch].y = jrel0 + k * 1024; ++nch;
    }
  }
  for (int i = nch; i < MAXCH; ++i) { ctab.e[i].x = 0; ctab.e[i].y = 0; }
  for (int bl = 0; bl < 16; ++bl) gc.ratio[bl] = (float)exp2((double)bl / 36.0);
  for (int b = 0; b < 256; ++b) {
    if (b < NBINS) {
      double freq = FMIND * exp2((double)b / 36.0);
      double L = Q * SRD / freq;
      int T = (int)(L * 0.5);
      double N = (double)(2 * T + 1);
      double win_sum = 0.5 * N - 0.5 * (sin(PI * (N - L) / L) / sin(PI / L));
      gc.Tfu[b] = (ushort_t)T;
      fc.nrm[b] = (float)(1.0 / (win_sum * sqrt(L)));
    } else {
      gc.Tfu[b] = 0; fc.nrm[b] = 0.0f;
    }
  }

  // ---- ws layout: partial only (nch * 8 ftiles * 2 planes * 1024 f32 = ~17 MB) ----
  float* partial = (float*)d_ws;

  cqt_fused<<<dim3(8, nch), 512, 0, stream>>>(sig, partial, ctab, gc);
  fin_kernel<<<dim3(16, 8), 256, 0, stream>>>(partial, out, fc);
}

// Round 10
// 122.386 us; speedup vs baseline: 1.3191x; 1.0797x over previous
//
#include <hip/hip_runtime.h>
#include <hip/hip_bf16.h>
#include <math.h>

// ---------------- CQT constants ----------------
#define NBINS    252
#define NFRAMES  456
#define HOPSZ    484
#define SIGLEN   220500
#define TSTART0  (-34688)      // most negative tap (T0=34682 rounded up to mult of 8)
#define SRD      44100.0
#define FMIND    32.70319566257483
#define MAXCH    264
#define FT       128           // frames per block
#define NFT      4             // frame tiles (512 frames >= 456)
#define PADBF    321536        // padded bf16 signal elems (covers max P0 + 65536)
#define AELEMS   65536         // A LDS elems (128 KiB), >= 127*484 + 1023 + pad

typedef unsigned short ushort_t;
typedef __attribute__((ext_vector_type(8))) short bf16x8;
typedef __attribute__((ext_vector_type(4))) float f32x4;

struct ChunkTab { int2 e[MAXCH]; };   // .x = group, .y = jrel (chunk tap start - TSTART0, mult of 8)
struct GroupC {                        // per-group bases + per-bin-in-group ratio + exact T
  float fosg[16];                      // freq/SR for bin 16g
  float invLg[16];                     // 1/L for bin 16g
  float ratio[16];                     // 2^(bl/36)
  ushort_t Tfu[256];                   // per-bin T (0 for nonexistent bins)
};
struct FinC { float nrm[256]; int2 gt[16]; };  // per-bin norm; per-group {chunk0, nchunks}

__device__ __forceinline__ ushort_t f2bf(float x) {
  __hip_bfloat16 h = __float2bfloat16(x);
  return *reinterpret_cast<ushort_t*>(&h);
}

// ---------------- prep: padded bf16 signal (one cvt per sample, total) ----------------
__global__ __launch_bounds__(256) void prep_kernel(const float* __restrict__ sig,
                                                   ushort_t* __restrict__ padbf) {
  int i = blockIdx.x * 256 + threadIdx.x;
  if (i < PADBF) {
    int s = i + TSTART0;
    float v = (s >= 0 && s < SIGLEN) ? sig[s] : 0.0f;
    padbf[i] = f2bf(v);
  }
}

// ---- B-fragment generation for one 4-ks sub-phase (one thread: 2 taps, kr+ki) ----
// buf layout per ks: [frag(0=kr,1=ki)*512 + lane*8 + j] bf16, ks-major 1024 elems.
__device__ __forceinline__ void gen_phase(ushort_t* __restrict__ buf, int sc,
                                          int tbase, int gks, int glane, int gj0,
                                          float fos, float invL, float Tf) {
  const int t0 = tbase + (sc * 4 + gks) * 32 + (glane >> 4) * 8 + gj0;
  ushort_t pr[2], pi[2];
#pragma unroll
  for (int j = 0; j < 2; ++j) {
    const float tt = (float)(t0 + j);
    float kr = 0.0f, ki = 0.0f;
    if (fabsf(tt) <= Tf) {
      float wv = 0.5f + 0.5f * __cosf(6.2831853f * (tt * invL));
      float r = fos * tt; r -= rintf(r);             // phase mod 1
      float sn, cs; __sincosf(6.2831853f * r, &sn, &cs);
      kr = wv * cs; ki = wv * sn;
    }
    pr[j] = f2bf(kr); pi[j] = f2bf(ki);
  }
  *reinterpret_cast<unsigned int*>(&buf[gks * 1024 + glane * 8 + gj0])       = *reinterpret_cast<unsigned int*>(pr);
  *reinterpret_cast<unsigned int*>(&buf[gks * 1024 + 512 + glane * 8 + gj0]) = *reinterpret_cast<unsigned int*>(pi);
}

// ---------------- fused: copy bf16 window to LDS + gen B in LDS, MFMA ----------------
// grid (NFT frame-tiles of 128, nch chunks), 1024 thr = 16 waves = 8 frame-octiles x {re,im}.
// A staged as a LINEAR bf16 segment (128 KiB) via pure uint4 copies (no cvt, no bounds:
// the padded bf16 signal covers the whole span). B double-buffered 4-ks sub-phases.
__global__ __launch_bounds__(1024) void cqt_fused(const ushort_t* __restrict__ padbf,
                                                  float* __restrict__ partial,
                                                  ChunkTab tab, GroupC gc) {
  __shared__ ushort_t Alds[AELEMS];       // 131,072 B
  __shared__ ushort_t Blds[2][4096];      // 2 x 8,192 B  (4 ks x 1024)

  const int tid = threadIdx.x;
  const int lane = tid & 63;
  const int w = tid >> 6;                 // 0..15
  const int c = blockIdx.y, ft = blockIdx.x;
  const int g = tab.e[c].x, jrel = tab.e[c].y;
  const int P0 = ft * FT * HOPSZ + jrel;  // mult of 8 elems -> 16B-aligned

  // ---- stage A: 8192 uint4 copies, coalesced, issued before gen phase 0 ----
  {
    const uint4* gs = reinterpret_cast<const uint4*>(padbf + P0) + tid;
    uint4* ls = reinterpret_cast<uint4*>(Alds) + tid;
#pragma unroll
    for (int q = 0; q < 8; ++q)
      ls[q * 1024] = gs[q * 1024];
  }

  // ---- per-thread gen constants (thread covers one (ks4, lane, j-pair) slot) ----
  const int gks = (tid >> 6) & 3;
  const int gj0 = (tid >> 8) * 2;
  const int gbl = lane & 15;
  const float fos  = gc.fosg[g]  * gc.ratio[gbl];
  const float invL = gc.invLg[g] * gc.ratio[gbl];
  const float Tf   = (float)gc.Tfu[g * 16 + gbl];
  const int tbase = TSTART0 + jrel;

  // ---- MFMA lane roles: wave (fq8 = frame-octile, ri = re/im) ----
  const int fq8 = w >> 1, ri = w & 1;
  const int bl = lane & 15, kb = lane >> 4;
  const ushort_t* Ab = &Alds[(fq8 * 16 + bl) * HOPSZ + kb * 8];

  f32x4 acc = {0.f, 0.f, 0.f, 0.f};

  gen_phase(Blds[0], 0, tbase, gks, lane, gj0, fos, invL, Tf);
  __syncthreads();                        // drains A copies + B phase 0

  for (int sc = 0; sc < 8; ++sc) {
    if (sc < 7)
      gen_phase(Blds[(sc + 1) & 1], sc + 1, tbase, gks, lane, gj0, fos, invL, Tf);
    const ushort_t* Bb = &Blds[sc & 1][ri * 512 + lane * 8];
#pragma unroll
    for (int k4 = 0; k4 < 4; ++k4) {
      const int ks = sc * 4 + k4;
      union { uint2 q[2]; bf16x8 v; } a;
      a.q[0] = *reinterpret_cast<const uint2*>(Ab + ks * 32);      // 8B-aligned
      a.q[1] = *reinterpret_cast<const uint2*>(Ab + ks * 32 + 4);
      union { uint4 q; bf16x8 v; } b;
      b.q = *reinterpret_cast<const uint4*>(Bb + k4 * 1024);
      acc = __builtin_amdgcn_mfma_f32_16x16x32_bf16(a.v, b.v, acc, 0, 0, 0);
    }
    __syncthreads();
  }

  // C/D: col = lane&15 (bin), row = kb*4 + r (frame-in-16)  [m89-verified]
  // partial flat: ((c*NFT+ft)*2 + ri)*2048 + fq8*256 + row*16 + bl
  float* pp = partial + (size_t)(((c * NFT + ft) * 2 + ri) * 2048 + fq8 * 256 + bl);
#pragma unroll
  for (int r = 0; r < 4; ++r)
    pp[(kb * 4 + r) * 16] = acc[r];
}

// ---------------- finalize: sum partials over a group's chunks, magnitude + norm ----
// grid (16 groups, NFT frame-tiles), 512 thr; float4 reads fully coalesced.
__global__ __launch_bounds__(512) void fin_kernel(const float* __restrict__ partial,
                                                  float* __restrict__ out, FinC fc) {
  const int g = blockIdx.x, ft = blockIdx.y;
  const int t = threadIdx.x;
  const int c0 = fc.gt[g].x, nc = fc.gt[g].y;

  float cr[4] = {0.f, 0.f, 0.f, 0.f}, ci[4] = {0.f, 0.f, 0.f, 0.f};
  for (int c = c0; c < c0 + nc; ++c) {
    const float4 vr = *reinterpret_cast<const float4*>(
        partial + (size_t)((c * NFT + ft) * 2 + 0) * 2048 + t * 4);
    const float4 vi = *reinterpret_cast<const float4*>(
        partial + (size_t)((c * NFT + ft) * 2 + 1) * 2048 + t * 4);
    cr[0] += vr.x; cr[1] += vr.y; cr[2] += vr.z; cr[3] += vr.w;
    ci[0] += vi.x; ci[1] += vi.y; ci[2] += vi.z; ci[3] += vi.w;
  }
#pragma unroll
  for (int i = 0; i < 4; ++i) {
    const int j = t * 4 + i;
    const int f = ft * FT + (j >> 4);
    const int b = g * 16 + (j & 15);
    if (f < NFRAMES && b < NBINS)
      out[(size_t)b * NFRAMES + f] = fc.nrm[b] * sqrtf(cr[i] * cr[i] + ci[i] * ci[i]);
  }
}

// ---------------- launch ----------------
extern "C" void kernel_launch(void* const* d_in, const int* in_sizes, int n_in,
                              void* d_out, int out_size, void* d_ws, size_t ws_size,
                              hipStream_t stream) {
  const float* sig = (const float*)d_in[0];
  float* out = (float*)d_out;
  char* ws = (char*)d_ws;

  // ---- host-side constant tables (pure arithmetic, identical every call) ----
  ChunkTab ctab; GroupC gc; FinC fc;
  const double PI = 3.14159265358979323846;
  const double Q = 1.0 / (exp2(1.0 / 36.0) - 1.0);
  int nch = 0;
  for (int g = 0; g < 16; ++g) {
    double freq = FMIND * exp2((double)(16 * g) / 36.0);
    double L = Q * SRD / freq;
    int T = (int)(L * 0.5);
    int r = (8 - (T & 7)) & 7;
    int tstart = -(T + r);                    // mult of 8
    int ntaps = 2 * T + 1 + r;
    int chunks = (ntaps + 1023) / 1024;
    gc.fosg[g] = (float)(freq / SRD);
    gc.invLg[g] = (float)(1.0 / L);
    fc.gt[g].x = nch; fc.gt[g].y = chunks;
    int jrel0 = tstart - TSTART0;             // >= 0, mult of 8
    for (int k = 0; k < chunks; ++k) {
      ctab.e[nch].x = g; ctab.e[nch].y = jrel0 + k * 1024; ++nch;
    }
  }
  for (int i = nch; i < MAXCH; ++i) { ctab.e[i].x = 0; ctab.e[i].y = 0; }
  for (int bl = 0; bl < 16; ++bl) gc.ratio[bl] = (float)exp2((double)bl / 36.0);
  for (int b = 0; b < 256; ++b) {
    if (b < NBINS) {
      double freq = FMIND * exp2((double)b / 36.0);
      double L = Q * SRD / freq;
      int T = (int)(L * 0.5);
      double N = (double)(2 * T + 1);
      double win_sum = 0.5 * N - 0.5 * (sin(PI * (N - L) / L) / sin(PI / L));
      gc.Tfu[b] = (ushort_t)T;
      fc.nrm[b] = (float)(1.0 / (win_sum * sqrt(L)));
    } else {
      gc.Tfu[b] = 0; fc.nrm[b] = 0.0f;
    }
  }

  // ---- ws layout: padbf (643,072 B) | partial (nch * NFT * 2 * 2048 f32 ~ 17 MB) ----
  ushort_t* padbf = (ushort_t*)ws;
  size_t off = ((size_t)PADBF * 2 + 255) & ~(size_t)255;
  float* partial = (float*)(ws + off);

  prep_kernel<<<(PADBF + 255) / 256, 256, 0, stream>>>(sig, padbf);
  cqt_fused<<<dim3(NFT, nch), 1024, 0, stream>>>(padbf, partial, ctab, gc);
  fin_kernel<<<dim3(16, NFT), 512, 0, stream>>>(partial, out, fc);
}